// Round 7
// baseline (244.120 us; speedup 1.0000x reference)
//
#include <hip/hip_runtime.h>
#include <math.h>

// Problem constants
#define NB   64      // batch
#define NPT  500     // entities == relations per image
#define C1   151     // classes incl. background
#define CM1  150     // kept classes
#define EAF  12      // ent aux floats/row {score,cx,cy,n2, x0,y0,x1,y1, area, pad*3}
#define RAF  20      // rel aux floats/row {rs box*4, ro box*4, vec*4, rsn2, ron2, aRs, aRo, pad*4}

// Swizzled prob layout (bf16): [img][g=row/16][kb=k/8][ir=row%16][8]
#define GRP_ELEMS  2560
#define IMG_ELEMS  (32 * GRP_ELEMS)
#define PROB_ELEMS ((size_t)NB * IMG_ELEMS)

typedef __bf16 bf16x8 __attribute__((ext_vector_type(8)));
typedef float  f32x4  __attribute__((ext_vector_type(4)));

__device__ __forceinline__ float rcpf(float x) { return __builtin_amdgcn_rcpf(x); }
__device__ __forceinline__ float rsqf(float x) { return __builtin_amdgcn_rsqf(x); }

// ---------------------------------------------------------------------------
// Kernel 1: 16 lanes per row, 16 rows per 256-thread block (unchanged).
// ---------------------------------------------------------------------------
extern "C" __global__ void __launch_bounds__(256)
k_pre(const float* __restrict__ boxes, const float* __restrict__ ent_logits,
      const float* __restrict__ ro_logits, const float* __restrict__ rs_logits,
      const float* __restrict__ ro_box, const float* __restrict__ rs_box,
      const float* __restrict__ rel_vec, const float* __restrict__ tsz,
      __bf16* __restrict__ entP, __bf16* __restrict__ rsP, __bf16* __restrict__ roP,
      float* __restrict__ entAux, float* __restrict__ relAux)
{
    const int tid = threadIdx.x;
    const int q   = tid & 15;
    const int rl  = tid >> 4;
    const int bx  = blockIdx.x;
    const int set = bx / 2000;
    const int rowIdx = (bx - set * 2000) * 16 + rl;
    const int b = rowIdx / 500;
    const int i = rowIdx - b * 500;

    const float* src = (set == 0 ? ent_logits : (set == 1 ? rs_logits : ro_logits))
                       + (size_t)rowIdx * C1;

    float x[10];
    #pragma unroll
    for (int t = 0; t < 9; ++t) x[t] = src[q + 16 * t];
    x[9] = (q <= 6) ? src[q + 144] : -INFINITY;

    float mAll = x[0];
    #pragma unroll
    for (int t = 1; t < 10; ++t) mAll = fmaxf(mAll, x[t]);
    float mKept = x[0];
    #pragma unroll
    for (int t = 1; t < 9; ++t) mKept = fmaxf(mKept, x[t]);
    if (q <= 5) mKept = fmaxf(mKept, x[9]);

    #pragma unroll
    for (int off = 1; off < 16; off <<= 1) {
        mAll  = fmaxf(mAll,  __shfl_xor(mAll,  off, 16));
        mKept = fmaxf(mKept, __shfl_xor(mKept, off, 16));
    }

    float e[10], s = 0.f, s2 = 0.f;
    #pragma unroll
    for (int t = 0; t < 9; ++t) {
        e[t] = __expf(x[t] - mAll);
        s  += e[t];
        s2 += e[t] * e[t];
    }
    e[9] = (q <= 6) ? __expf(x[9] - mAll) : 0.f;
    s += e[9];
    if (q <= 5) s2 += e[9] * e[9];

    #pragma unroll
    for (int off = 1; off < 16; off <<= 1) {
        s  += __shfl_xor(s,  off, 16);
        s2 += __shfl_xor(s2, off, 16);
    }

    const float inv = rcpf(s);
    const float pm  = __expf(mKept - mAll) * inv;
    const float nn  = s2 * inv * inv;

    __bf16* dstT = (set == 0 ? entP : (set == 1 ? rsP : roP));
    const int g  = i >> 4, ir = i & 15;
    __bf16* dst = dstT + ((size_t)b * 32 + g) * GRP_ELEMS + ir * 8 + (q & 7);
    const int qh = q >> 3;
    #pragma unroll
    for (int t = 0; t < 9; ++t)
        dst[(2 * t + qh) * 128] = (__bf16)(e[t] * inv);
    dst[(18 + qh) * 128] = (q <= 5) ? (__bf16)(e[9] * inv) : (__bf16)0.f;

    if (q == 0) {
        const float hh = tsz[b * 2 + 0];
        const float ww = tsz[b * 2 + 1];
        if (set == 0) {
            const float* bb = boxes + (size_t)rowIdx * 4;
            const float cx = bb[0], cy = bb[1], bw = bb[2], bh = bb[3];
            const float X0 = (cx - 0.5f * bw) * ww, Y0 = (cy - 0.5f * bh) * hh;
            const float X1 = (cx + 0.5f * bw) * ww, Y1 = (cy + 0.5f * bh) * hh;
            float* A = entAux + (size_t)rowIdx * EAF;
            A[0] = pm;
            A[1] = 0.5f * (X0 + X1);
            A[2] = 0.5f * (Y0 + Y1);
            A[3] = nn;
            A[4] = X0; A[5] = Y0; A[6] = X1; A[7] = Y1;
            A[8] = (X1 - X0) * (Y1 - Y0);
        } else if (set == 1) {
            const float* bb = rs_box  + (size_t)rowIdx * 4;
            const float* vv = rel_vec + (size_t)rowIdx * 4;
            const float cx = bb[0], cy = bb[1], bw = bb[2], bh = bb[3];
            float* A = relAux + (size_t)rowIdx * RAF;
            const float X0 = (cx - 0.5f * bw) * ww, Y0 = (cy - 0.5f * bh) * hh;
            const float X1 = (cx + 0.5f * bw) * ww, Y1 = (cy + 0.5f * bh) * hh;
            A[0] = X0; A[1] = Y0; A[2] = X1; A[3] = Y1;
            A[8]  = vv[0] * ww; A[9]  = vv[1] * hh;
            A[10] = vv[2] * ww; A[11] = vv[3] * hh;
            A[12] = nn;
            A[14] = (X1 - X0) * (Y1 - Y0);
        } else {
            const float* bb = ro_box + (size_t)rowIdx * 4;
            const float cx = bb[0], cy = bb[1], bw = bb[2], bh = bb[3];
            float* A = relAux + (size_t)rowIdx * RAF;
            const float X0 = (cx - 0.5f * bw) * ww, Y0 = (cy - 0.5f * bh) * hh;
            const float X1 = (cx + 0.5f * bw) * ww, Y1 = (cy + 0.5f * bh) * hh;
            A[4] = X0; A[5] = Y0; A[6] = X1; A[7] = Y1;
            A[13] = nn;
            A[15] = (X1 - X0) * (Y1 - Y0);
        }
    }
}

// ---------------------------------------------------------------------------
// Epilogue for swapped layout: D row = e (kq*4+reg), col = r (lane&15).
// Each lane: ONE r (aux loaded once), 16 e values, float4 stores.
// ---------------------------------------------------------------------------
template <bool FULL>
__device__ __forceinline__ void epilogue(
    const float (*eA)[EAF], const float (*rA)[RAF],
    const f32x4* accS, const f32x4* accO,
    int lr, int kq, int wv, int b, int e0T, int r0T,
    float* __restrict__ outS, float* __restrict__ outO)
{
    const int rIdx = wv * 16 + lr;
    const int gr   = r0T + rIdx;
    const float* rp = rA[rIdx];
    const f32x4 rsB = *(const f32x4*)(rp);        // rs box
    const f32x4 roB = *(const f32x4*)(rp + 4);    // ro box
    const f32x4 vv  = *(const f32x4*)(rp + 8);    // vec: sx, sy, ox, oy
    const f32x4 rn  = *(const f32x4*)(rp + 12);   // rsn2, ron2, areaRs, areaRo
    const bool rOK  = FULL || (gr < NPT);
    const unsigned rowOff = ((unsigned)b * NPT + (unsigned)gr) * NPT;

    #pragma unroll
    for (int et = 0; et < 4; ++et) {
        float4 vS, vO;
        float* pS = (float*)&vS;
        float* pO = (float*)&vO;
        #pragma unroll
        for (int reg = 0; reg < 4; ++reg) {
            const int eIdx = et * 16 + kq * 4 + reg;
            const float* ep = eA[eIdx];
            const f32x4 ev0 = *(const f32x4*)(ep);       // score, cx, cy, n2
            const f32x4 ev1 = *(const f32x4*)(ep + 4);   // x0, y0, x1, y1
            const float aE  = ep[8];
            const float score = ev0[0], ecx = ev0[1], ecy = ev0[2], en2 = ev0[3];
            const float ex0 = ev1[0], ey0 = ev1[1], ex1 = ev1[2], ey1 = ev1[3];

            const float iwS = fmaxf(fminf(ex1, rsB[2]) - fmaxf(ex0, rsB[0]), 0.f);
            const float ihS = fmaxf(fminf(ey1, rsB[3]) - fmaxf(ey0, rsB[1]), 0.f);
            const float inS = iwS * ihS;
            const float unS = aE + rn[2] - inS;
            const float aCS = (fmaxf(ex1, rsB[2]) - fminf(ex0, rsB[0]))
                            * (fmaxf(ey1, rsB[3]) - fminf(ey0, rsB[1]));
            const float gS  = fmaxf(fmaf(inS, rcpf(unS), fmaf(unS, rcpf(aCS), -1.f)), 0.f);

            const float iwO = fmaxf(fminf(ex1, roB[2]) - fmaxf(ex0, roB[0]), 0.f);
            const float ihO = fmaxf(fminf(ey1, roB[3]) - fmaxf(ey0, roB[1]), 0.f);
            const float inO = iwO * ihO;
            const float unO = aE + rn[3] - inO;
            const float aCO = (fmaxf(ex1, roB[2]) - fminf(ex0, roB[0]))
                            * (fmaxf(ey1, roB[3]) - fminf(ey0, roB[1]));
            const float gO  = fmaxf(fmaf(inO, rcpf(unO), fmaf(unO, rcpf(aCO), -1.f)), 0.f);

            const float d2s = fmaxf(fmaf(-2.f, accS[et][reg], rn[0] + en2), 1e-12f);
            const float d2o = fmaxf(fmaf(-2.f, accO[et][reg], rn[1] + en2), 1e-12f);
            const float dS  = d2s * rsqf(d2s);
            const float dO  = d2o * rsqf(d2o);
            const float distS = fabsf(vv[0] - ecx) + fabsf(vv[1] - ecy);
            const float distO = fabsf(vv[2] - ecx) + fabsf(vv[3] - ecy);
            const float qS = rcpf((distS + 1.f) * (dS + 1.f));
            const float qO = rcpf((distO + 1.f) * (dO + 1.f));

            pS[reg] = score * qS * gS;
            pO[reg] = score * qO * gO;
        }
        const int eBase = e0T + et * 16 + kq * 4;   // multiple of 4; 500%4==0
        if (rOK && (FULL || eBase < NPT)) {
            const unsigned o = rowOff + (unsigned)eBase;
            *(float4*)(outS + o) = vS;
            *(float4*)(outO + o) = vO;
        }
    }
}

// ---------------------------------------------------------------------------
// Kernel 2: 64r x 64e tile per block.
// NEW: the 20 KB ent tile (4 swizzle groups, contiguous) is staged to LDS
// ONCE per block via async global_load_lds width=16 (was loaded 4x redundantly
// from L2 by each wave). All 10 r-side fragment loads hoisted into registers
// before the barrier. K-loop: ds_read_b128 + MFMA only.
// ---------------------------------------------------------------------------
extern "C" __global__ void __launch_bounds__(256, 4)
k_main(const __bf16* __restrict__ entP, const __bf16* __restrict__ rsP,
       const __bf16* __restrict__ roP, const float* __restrict__ eAuxG,
       const float* __restrict__ rAuxG,
       float* __restrict__ outS, float* __restrict__ outO)
{
    __shared__ __align__(16) __bf16 sEnt[4 * GRP_ELEMS];   // 20 KB
    __shared__ __align__(16) float eA[64][EAF];
    __shared__ __align__(16) float rA[64][RAF];

    const int tid = threadIdx.x;
    const int b   = blockIdx.x;
    const int e0T = (blockIdx.y & 7) * 64;
    const int r0T = (blockIdx.y >> 3) * 64;

    const int wv   = tid >> 6;
    const int lane = tid & 63;
    const int lr   = lane & 15;
    const int kq   = lane >> 4;

    const int gR = (r0T >> 4) + wv;
    const int gE = (e0T >> 4);
    const __bf16* rsBase  = rsP  + ((size_t)b * 32 + gR) * GRP_ELEMS + lr * 8;
    const __bf16* roBase  = roP  + ((size_t)b * 32 + gR) * GRP_ELEMS + lr * 8;
    const __bf16* entSrc  = entP + ((size_t)b * 32 + gE) * GRP_ELEMS;   // 20480 B contiguous

    // ---- hoist ALL r-side fragment loads (10 x 16 B per lane) ----
    bf16x8 brs[5], bro[5];
    #pragma unroll
    for (int ks = 0; ks < 5; ++ks) {
        const int kOff = (ks * 4 + kq) * 128;
        brs[ks] = *(const bf16x8*)(rsBase + kOff);
        bro[ks] = *(const bf16x8*)(roBase + kOff);
    }

    // ---- async stage ent tile to LDS: 5 iters x (4 waves x 1 KB) = 20 KB ----
    #pragma unroll
    for (int it = 0; it < 5; ++it) {
        const int off = it * 4096 + wv * 1024;            // wave-uniform byte offset
        __builtin_amdgcn_global_load_lds(
            (const __attribute__((address_space(1))) unsigned int*)
                ((const char*)entSrc + off + lane * 16),
            (__attribute__((address_space(3))) unsigned int*)
                ((char*)sEnt + off),
            16, 0, 0);
    }

    // ---- stage aux to LDS ----
    {
        const float4 z = {0.f, 0.f, 0.f, 0.f};
        for (int t = tid; t < 64 * (EAF / 4); t += 256) {
            const int e = t / (EAF / 4), qq = t % (EAF / 4);
            const int ge = e0T + e;
            ((float4*)eA[e])[qq] = (ge < NPT)
                ? ((const float4*)(eAuxG + ((size_t)b * NPT + ge) * EAF))[qq] : z;
        }
        for (int t = tid; t < 64 * (RAF / 4); t += 256) {
            const int r = t / (RAF / 4), qq = t % (RAF / 4);
            const int gr = r0T + r;
            ((float4*)rA[r])[qq] = (gr < NPT)
                ? ((const float4*)(rAuxG + ((size_t)b * NPT + gr) * RAF))[qq] : z;
        }
    }
    __syncthreads();   // drains vmcnt (incl. global_load_lds) + barrier

    f32x4 accS[4] = {{0,0,0,0},{0,0,0,0},{0,0,0,0},{0,0,0,0}};
    f32x4 accO[4] = {{0,0,0,0},{0,0,0,0},{0,0,0,0},{0,0,0,0}};

    #pragma unroll
    for (int ks = 0; ks < 5; ++ks) {
        const int kOff = (ks * 4 + kq) * 128 + lr * 8;
        #pragma unroll
        for (int et = 0; et < 4; ++et) {
            const bf16x8 ae = *(const bf16x8*)&sEnt[et * GRP_ELEMS + kOff];
            accS[et] = __builtin_amdgcn_mfma_f32_16x16x32_bf16(ae, brs[ks], accS[et], 0, 0, 0);
            accO[et] = __builtin_amdgcn_mfma_f32_16x16x32_bf16(ae, bro[ks], accO[et], 0, 0, 0);
        }
    }

    if (e0T + 64 <= NPT && r0T + 64 <= NPT) {
        epilogue<true >(eA, rA, accS, accO, lr, kq, wv, b, e0T, r0T, outS, outO);
    } else {
        epilogue<false>(eA, rA, accS, accO, lr, kq, wv, b, e0T, r0T, outS, outO);
    }
}

// ---------------------------------------------------------------------------
extern "C" void kernel_launch(void* const* d_in, const int* in_sizes, int n_in,
                              void* d_out, int out_size, void* d_ws, size_t ws_size,
                              hipStream_t stream)
{
    const float* boxes      = (const float*)d_in[0];
    const float* ent_logits = (const float*)d_in[1];
    const float* ro_logits  = (const float*)d_in[2];
    const float* rs_logits  = (const float*)d_in[3];
    const float* ro_box     = (const float*)d_in[4];
    const float* rs_box     = (const float*)d_in[5];
    const float* rel_vec    = (const float*)d_in[6];
    const float* tsz        = (const float*)d_in[7];

    __bf16* entP = (__bf16*)d_ws;
    __bf16* rsP  = entP + PROB_ELEMS;
    __bf16* roP  = rsP  + PROB_ELEMS;
    float*  eAux = (float*)(roP + PROB_ELEMS);
    float*  rAux = eAux + (size_t)NB * NPT * EAF;

    float* outS = (float*)d_out;
    float* outO = outS + (size_t)NB * NPT * NPT;

    hipLaunchKernelGGL(k_pre, dim3(6000), dim3(256), 0, stream,
                       boxes, ent_logits, ro_logits, rs_logits,
                       ro_box, rs_box, rel_vec, tsz,
                       entP, rsP, roP, eAux, rAux);

    hipLaunchKernelGGL(k_main, dim3(64, 64), dim3(256), 0, stream,
                       entP, rsP, roP, eAux, rAux, outS, outO);
}

// Round 8
// 234.997 us; speedup vs baseline: 1.0388x; 1.0388x over previous
//
#include <hip/hip_runtime.h>
#include <math.h>

// Problem constants
#define NB   64      // batch
#define NPT  500     // entities == relations per image
#define C1   151     // classes incl. background
#define CM1  150     // kept classes
#define EAF  12      // ent aux floats/row {score,cx,cy,n2, x0,y0,x1,y1, area, pad*3}
#define RAF  20      // rel aux floats/row {rs box*4, ro box*4, vec*4, rsn2, ron2, aRs, aRo, pad*4}

// Swizzled prob layout (bf16): [img][g=row/16][kb=k/8][ir=row%16][8]
#define GRP_ELEMS  2560
#define IMG_ELEMS  (32 * GRP_ELEMS)
#define PROB_ELEMS ((size_t)NB * IMG_ELEMS)

typedef __bf16 bf16x8 __attribute__((ext_vector_type(8)));
typedef float  f32x4  __attribute__((ext_vector_type(4)));

__device__ __forceinline__ float rcpf(float x) { return __builtin_amdgcn_rcpf(x); }
__device__ __forceinline__ float rsqf(float x) { return __builtin_amdgcn_rsqf(x); }

// ---------------------------------------------------------------------------
// Kernel 1: 16 lanes per row, 16 rows per 256-thread block (unchanged).
// ---------------------------------------------------------------------------
extern "C" __global__ void __launch_bounds__(256)
k_pre(const float* __restrict__ boxes, const float* __restrict__ ent_logits,
      const float* __restrict__ ro_logits, const float* __restrict__ rs_logits,
      const float* __restrict__ ro_box, const float* __restrict__ rs_box,
      const float* __restrict__ rel_vec, const float* __restrict__ tsz,
      __bf16* __restrict__ entP, __bf16* __restrict__ rsP, __bf16* __restrict__ roP,
      float* __restrict__ entAux, float* __restrict__ relAux)
{
    const int tid = threadIdx.x;
    const int q   = tid & 15;
    const int rl  = tid >> 4;
    const int bx  = blockIdx.x;
    const int set = bx / 2000;
    const int rowIdx = (bx - set * 2000) * 16 + rl;
    const int b = rowIdx / 500;
    const int i = rowIdx - b * 500;

    const float* src = (set == 0 ? ent_logits : (set == 1 ? rs_logits : ro_logits))
                       + (size_t)rowIdx * C1;

    float x[10];
    #pragma unroll
    for (int t = 0; t < 9; ++t) x[t] = src[q + 16 * t];
    x[9] = (q <= 6) ? src[q + 144] : -INFINITY;

    float mAll = x[0];
    #pragma unroll
    for (int t = 1; t < 10; ++t) mAll = fmaxf(mAll, x[t]);
    float mKept = x[0];
    #pragma unroll
    for (int t = 1; t < 9; ++t) mKept = fmaxf(mKept, x[t]);
    if (q <= 5) mKept = fmaxf(mKept, x[9]);

    #pragma unroll
    for (int off = 1; off < 16; off <<= 1) {
        mAll  = fmaxf(mAll,  __shfl_xor(mAll,  off, 16));
        mKept = fmaxf(mKept, __shfl_xor(mKept, off, 16));
    }

    float e[10], s = 0.f, s2 = 0.f;
    #pragma unroll
    for (int t = 0; t < 9; ++t) {
        e[t] = __expf(x[t] - mAll);
        s  += e[t];
        s2 += e[t] * e[t];
    }
    e[9] = (q <= 6) ? __expf(x[9] - mAll) : 0.f;
    s += e[9];
    if (q <= 5) s2 += e[9] * e[9];

    #pragma unroll
    for (int off = 1; off < 16; off <<= 1) {
        s  += __shfl_xor(s,  off, 16);
        s2 += __shfl_xor(s2, off, 16);
    }

    const float inv = rcpf(s);
    const float pm  = __expf(mKept - mAll) * inv;
    const float nn  = s2 * inv * inv;

    __bf16* dstT = (set == 0 ? entP : (set == 1 ? rsP : roP));
    const int g  = i >> 4, ir = i & 15;
    __bf16* dst = dstT + ((size_t)b * 32 + g) * GRP_ELEMS + ir * 8 + (q & 7);
    const int qh = q >> 3;
    #pragma unroll
    for (int t = 0; t < 9; ++t)
        dst[(2 * t + qh) * 128] = (__bf16)(e[t] * inv);
    dst[(18 + qh) * 128] = (q <= 5) ? (__bf16)(e[9] * inv) : (__bf16)0.f;

    if (q == 0) {
        const float hh = tsz[b * 2 + 0];
        const float ww = tsz[b * 2 + 1];
        if (set == 0) {
            const float* bb = boxes + (size_t)rowIdx * 4;
            const float cx = bb[0], cy = bb[1], bw = bb[2], bh = bb[3];
            const float X0 = (cx - 0.5f * bw) * ww, Y0 = (cy - 0.5f * bh) * hh;
            const float X1 = (cx + 0.5f * bw) * ww, Y1 = (cy + 0.5f * bh) * hh;
            float* A = entAux + (size_t)rowIdx * EAF;
            A[0] = pm;
            A[1] = 0.5f * (X0 + X1);
            A[2] = 0.5f * (Y0 + Y1);
            A[3] = nn;
            A[4] = X0; A[5] = Y0; A[6] = X1; A[7] = Y1;
            A[8] = (X1 - X0) * (Y1 - Y0);
        } else if (set == 1) {
            const float* bb = rs_box  + (size_t)rowIdx * 4;
            const float* vv = rel_vec + (size_t)rowIdx * 4;
            const float cx = bb[0], cy = bb[1], bw = bb[2], bh = bb[3];
            float* A = relAux + (size_t)rowIdx * RAF;
            const float X0 = (cx - 0.5f * bw) * ww, Y0 = (cy - 0.5f * bh) * hh;
            const float X1 = (cx + 0.5f * bw) * ww, Y1 = (cy + 0.5f * bh) * hh;
            A[0] = X0; A[1] = Y0; A[2] = X1; A[3] = Y1;
            A[8]  = vv[0] * ww; A[9]  = vv[1] * hh;
            A[10] = vv[2] * ww; A[11] = vv[3] * hh;
            A[12] = nn;
            A[14] = (X1 - X0) * (Y1 - Y0);
        } else {
            const float* bb = ro_box + (size_t)rowIdx * 4;
            const float cx = bb[0], cy = bb[1], bw = bb[2], bh = bb[3];
            float* A = relAux + (size_t)rowIdx * RAF;
            const float X0 = (cx - 0.5f * bw) * ww, Y0 = (cy - 0.5f * bh) * hh;
            const float X1 = (cx + 0.5f * bw) * ww, Y1 = (cy + 0.5f * bh) * hh;
            A[4] = X0; A[5] = Y0; A[6] = X1; A[7] = Y1;
            A[13] = nn;
            A[15] = (X1 - X0) * (Y1 - Y0);
        }
    }
}

// ---------------------------------------------------------------------------
// Epilogue, R4 layout: D row = r (kq*4+reg), col = e (lane&15).
// e-aux hoisted to registers (4 et groups); 4 r rows read from LDS.
// giou with single rcp: g = (in*aC + un^2)*rcp(un*aC) - 1.
// ---------------------------------------------------------------------------
template <bool FULL>
__device__ __forceinline__ void epilogue(
    const float (*eA)[EAF], const float (*rA)[RAF],
    const f32x4* accS, const f32x4* accO,
    int lr, int kq, int wv, int b, int e0T, int r0T,
    float* __restrict__ outS, float* __restrict__ outO)
{
    f32x4 ev0[4], ev1[4];
    float eArea[4];
    #pragma unroll
    for (int et = 0; et < 4; ++et) {
        const float* ep = eA[et * 16 + lr];
        ev0[et] = *(const f32x4*)(ep);       // score, cx, cy, n2
        ev1[et] = *(const f32x4*)(ep + 4);   // x0, y0, x1, y1
        eArea[et] = ep[8];
    }

    const unsigned baseR0 = ((unsigned)b * NPT + (unsigned)(r0T + wv * 16 + kq * 4)) * NPT;
    const unsigned eBase  = (unsigned)(e0T + lr);

    #pragma unroll
    for (int reg = 0; reg < 4; ++reg) {
        const int rIdx = wv * 16 + kq * 4 + reg;
        const bool rOK = FULL || (r0T + rIdx < NPT);
        const float* rp = rA[rIdx];
        const f32x4 rsB = *(const f32x4*)(rp);        // rs box
        const f32x4 roB = *(const f32x4*)(rp + 4);    // ro box
        const f32x4 vv  = *(const f32x4*)(rp + 8);    // vec: sx, sy, ox, oy
        const f32x4 rn  = *(const f32x4*)(rp + 12);   // rsn2, ron2, areaRs, areaRo
        const unsigned rowOff = baseR0 + (unsigned)reg * NPT;

        #pragma unroll
        for (int et = 0; et < 4; ++et) {
            const float score = ev0[et][0], ecx = ev0[et][1], ecy = ev0[et][2], en2 = ev0[et][3];
            const float ex0 = ev1[et][0], ey0 = ev1[et][1], ex1 = ev1[et][2], ey1 = ev1[et][3];
            const float aE = eArea[et];

            const float iwS = fmaxf(fminf(ex1, rsB[2]) - fmaxf(ex0, rsB[0]), 0.f);
            const float ihS = fmaxf(fminf(ey1, rsB[3]) - fmaxf(ey0, rsB[1]), 0.f);
            const float inS = iwS * ihS;
            const float unS = aE + rn[2] - inS;
            const float aCS = (fmaxf(ex1, rsB[2]) - fminf(ex0, rsB[0]))
                            * (fmaxf(ey1, rsB[3]) - fminf(ey0, rsB[1]));
            const float gS  = fmaxf(fmaf(fmaf(inS, aCS, unS * unS), rcpf(unS * aCS), -1.f), 0.f);

            const float iwO = fmaxf(fminf(ex1, roB[2]) - fmaxf(ex0, roB[0]), 0.f);
            const float ihO = fmaxf(fminf(ey1, roB[3]) - fmaxf(ey0, roB[1]), 0.f);
            const float inO = iwO * ihO;
            const float unO = aE + rn[3] - inO;
            const float aCO = (fmaxf(ex1, roB[2]) - fminf(ex0, roB[0]))
                            * (fmaxf(ey1, roB[3]) - fminf(ey0, roB[1]));
            const float gO  = fmaxf(fmaf(fmaf(inO, aCO, unO * unO), rcpf(unO * aCO), -1.f), 0.f);

            const float d2s = fmaxf(fmaf(-2.f, accS[et][reg], rn[0] + en2), 1e-12f);
            const float d2o = fmaxf(fmaf(-2.f, accO[et][reg], rn[1] + en2), 1e-12f);
            const float dS  = d2s * rsqf(d2s);
            const float dO  = d2o * rsqf(d2o);
            const float distS = fabsf(vv[0] - ecx) + fabsf(vv[1] - ecy);
            const float distO = fabsf(vv[2] - ecx) + fabsf(vv[3] - ecy);
            const float qS = rcpf((distS + 1.f) * (dS + 1.f));
            const float qO = rcpf((distO + 1.f) * (dO + 1.f));

            const float vS = score * qS * gS;
            const float vO = score * qO * gO;

            const unsigned o = rowOff + eBase + (unsigned)(et * 16);
            if (FULL || (rOK && (int)(eBase + et * 16) < NPT)) {
                outS[o] = vS;
                outO[o] = vO;
            }
        }
    }
}

// ---------------------------------------------------------------------------
// Kernel 2: 64r x 64e tile per block. K-loop: rel fragments hoisted to regs,
// 20 KB ent tile staged to LDS once via async global_load_lds (width=16).
// MFMA operand order: mfma(rel, ent, acc) -> D row=r, col=e (R4 layout; the
// swapped order's 16-rows*64B store pattern cost +30 MB partial-line
// writebacks and 14 us — R5/R6 post-mortem).
// ---------------------------------------------------------------------------
extern "C" __global__ void __launch_bounds__(256, 4)
k_main(const __bf16* __restrict__ entP, const __bf16* __restrict__ rsP,
       const __bf16* __restrict__ roP, const float* __restrict__ eAuxG,
       const float* __restrict__ rAuxG,
       float* __restrict__ outS, float* __restrict__ outO)
{
    __shared__ __align__(16) __bf16 sEnt[4 * GRP_ELEMS];   // 20 KB
    __shared__ __align__(16) float eA[64][EAF];
    __shared__ __align__(16) float rA[64][RAF];

    const int tid = threadIdx.x;
    const int b   = blockIdx.x;
    const int e0T = (blockIdx.y & 7) * 64;
    const int r0T = (blockIdx.y >> 3) * 64;

    const int wv   = tid >> 6;
    const int lane = tid & 63;
    const int lr   = lane & 15;
    const int kq   = lane >> 4;

    const int gR = (r0T >> 4) + wv;
    const int gE = (e0T >> 4);
    const __bf16* rsBase = rsP  + ((size_t)b * 32 + gR) * GRP_ELEMS + lr * 8;
    const __bf16* roBase = roP  + ((size_t)b * 32 + gR) * GRP_ELEMS + lr * 8;
    const __bf16* entSrc = entP + ((size_t)b * 32 + gE) * GRP_ELEMS;   // 20480 B contiguous

    // ---- hoist rel-side fragment loads (A operand, 10 x 16 B per lane) ----
    bf16x8 ars[5], aro[5];
    #pragma unroll
    for (int ks = 0; ks < 5; ++ks) {
        const int kOff = (ks * 4 + kq) * 128;
        ars[ks] = *(const bf16x8*)(rsBase + kOff);
        aro[ks] = *(const bf16x8*)(roBase + kOff);
    }

    // ---- async stage ent tile to LDS: 5 iters x (4 waves x 1 KB) = 20 KB ----
    #pragma unroll
    for (int it = 0; it < 5; ++it) {
        const int off = it * 4096 + wv * 1024;            // wave-uniform byte offset
        __builtin_amdgcn_global_load_lds(
            (const __attribute__((address_space(1))) unsigned int*)
                ((const char*)entSrc + off + lane * 16),
            (__attribute__((address_space(3))) unsigned int*)
                ((char*)sEnt + off),
            16, 0, 0);
    }

    // ---- stage aux to LDS ----
    {
        const float4 z = {0.f, 0.f, 0.f, 0.f};
        for (int t = tid; t < 64 * (EAF / 4); t += 256) {
            const int e = t / (EAF / 4), qq = t % (EAF / 4);
            const int ge = e0T + e;
            ((float4*)eA[e])[qq] = (ge < NPT)
                ? ((const float4*)(eAuxG + ((size_t)b * NPT + ge) * EAF))[qq] : z;
        }
        for (int t = tid; t < 64 * (RAF / 4); t += 256) {
            const int r = t / (RAF / 4), qq = t % (RAF / 4);
            const int gr = r0T + r;
            ((float4*)rA[r])[qq] = (gr < NPT)
                ? ((const float4*)(rAuxG + ((size_t)b * NPT + gr) * RAF))[qq] : z;
        }
    }
    __syncthreads();   // drains vmcnt (incl. global_load_lds) + barrier

    f32x4 accS[4] = {{0,0,0,0},{0,0,0,0},{0,0,0,0},{0,0,0,0}};
    f32x4 accO[4] = {{0,0,0,0},{0,0,0,0},{0,0,0,0},{0,0,0,0}};

    #pragma unroll
    for (int ks = 0; ks < 5; ++ks) {
        const int kOff = (ks * 4 + kq) * 128 + lr * 8;
        #pragma unroll
        for (int et = 0; et < 4; ++et) {
            const bf16x8 be = *(const bf16x8*)&sEnt[et * GRP_ELEMS + kOff];
            accS[et] = __builtin_amdgcn_mfma_f32_16x16x32_bf16(ars[ks], be, accS[et], 0, 0, 0);
            accO[et] = __builtin_amdgcn_mfma_f32_16x16x32_bf16(aro[ks], be, accO[et], 0, 0, 0);
        }
    }

    if (e0T + 64 <= NPT && r0T + 64 <= NPT) {
        epilogue<true >(eA, rA, accS, accO, lr, kq, wv, b, e0T, r0T, outS, outO);
    } else {
        epilogue<false>(eA, rA, accS, accO, lr, kq, wv, b, e0T, r0T, outS, outO);
    }
}

// ---------------------------------------------------------------------------
extern "C" void kernel_launch(void* const* d_in, const int* in_sizes, int n_in,
                              void* d_out, int out_size, void* d_ws, size_t ws_size,
                              hipStream_t stream)
{
    const float* boxes      = (const float*)d_in[0];
    const float* ent_logits = (const float*)d_in[1];
    const float* ro_logits  = (const float*)d_in[2];
    const float* rs_logits  = (const float*)d_in[3];
    const float* ro_box     = (const float*)d_in[4];
    const float* rs_box     = (const float*)d_in[5];
    const float* rel_vec    = (const float*)d_in[6];
    const float* tsz        = (const float*)d_in[7];

    __bf16* entP = (__bf16*)d_ws;
    __bf16* rsP  = entP + PROB_ELEMS;
    __bf16* roP  = rsP  + PROB_ELEMS;
    float*  eAux = (float*)(roP + PROB_ELEMS);
    float*  rAux = eAux + (size_t)NB * NPT * EAF;

    float* outS = (float*)d_out;
    float* outO = outS + (size_t)NB * NPT * NPT;

    hipLaunchKernelGGL(k_pre, dim3(6000), dim3(256), 0, stream,
                       boxes, ent_logits, ro_logits, rs_logits,
                       ro_box, rs_box, rel_vec, tsz,
                       entP, rsP, roP, eAux, rAux);

    hipLaunchKernelGGL(k_main, dim3(64, 64), dim3(256), 0, stream,
                       entP, rsP, roP, eAux, rAux, outS, outO);
}